// Round 3
// baseline (125.075 us; speedup 1.0000x reference)
//
#include <hip/hip_runtime.h>
#include <math.h>

#define BB 8
#define CC 64
#define HH 32
#define WW 32
#define HW 1024
#define NEGN 256
#define TEMP 2.0f
#define FACTOR 0.8f
#define EPSF 1e-8f
#define PT 8            // p-rows per block
#define NTILE 128       // blocks per sample = HW / PT

// ws layout (floats):
//   part   [BB*NTILE*NEGN]  per-block per-n partial sums       (1 MB)
//   s0part [BB*NTILE]       per-block sim0 partial sums
//   bres   [BB*3]           per-b (S_b, L_b, sim0_b)
//   counter[1]              finalize arrival counter (zeroed by main blk 0)
#define WS_PART   0
#define WS_S0PART (BB * NTILE * NEGN)
#define WS_BRES   (WS_S0PART + BB * NTILE)
#define WS_CNT    (WS_BRES + BB * 3)

// ---------------------------------------------------------------------------
// Fused main kernel: one block per (b, 8-row p-tile).
// Phase A: dense GEMM D[pp][q] = sum_c z1[c,p]*z2[c,q], coalesced float4
//          streaming of z2[b]; 1/|z2_q| folded into D at LDS-write time.
// Phase B: per-(p,n) LDS gather + weight (half-wave shuffle reduce) + sim;
//          per-block partial sums stored to unique ws slots (no atomics).
// LDS: union(As 2K, simpart 8K) + Dt 32K + imgs 12K + z1sqs = 52.2 KB
//      -> 3 blocks/CU.
// ---------------------------------------------------------------------------
__global__ __launch_bounds__(256) void contrastive_fused(
    const float* __restrict__ z1,    // (B, C, HW)
    const float* __restrict__ z2,    // (B, C, HW)
    const float* __restrict__ img,   // (3, HW)
    const int*   __restrict__ nidx,  // (B, 2, HW, NEG)
    float* __restrict__ ws)
{
    // 2048 (As[512] / simpart[2048] union) + 8192 Dt + 3072 imgs + 8 z1sqs
    __shared__ float smem[2048 + PT * HW + 3 * HW + PT];
    float* const un    = smem;                 // As_s: [k][pp] (512) / simpart: [pp][n] (2048)
    float* const Dt_s  = smem + 2048;          // [pp][q], pre-divided by |z2_q|
    float* const imgs  = Dt_s + PT * HW;       // (3, HW)
    float* const z1sqs = imgs + 3 * HW;        // [pp]

    const int t  = threadIdx.x;
    const int b  = blockIdx.x >> 7;
    const int tile = blockIdx.x & (NTILE - 1);
    const int p0 = tile * PT;

    const int lane32 = t & 31;   // n-group lane
    const int pp_b   = t >> 5;   // p handled by this thread in phase B
    const int p_b    = p0 + pp_b;

    if (blockIdx.x == 0 && t == 0)
        ((int*)ws)[WS_CNT] = 0;          // arm finalize's last-block counter

    // ---- prefetch nidx early (n = lane32 + 32*j) ----
    int rr[8], cc_[8];
    const size_t nbase = ((size_t)(b * 2) * HW + p_b) * NEGN;
    #pragma unroll
    for (int j = 0; j < 8; ++j) {
        rr[j]  = nidx[nbase + lane32 + 32 * j];
        cc_[j] = nidx[nbase + (size_t)HW * NEGN + lane32 + 32 * j];
    }

    // ---- stage z1 panel + img into LDS ----
    for (int i = t; i < CC * PT; i += 256) {
        const int c = i >> 3, pp = i & 7;
        un[i] = z1[((size_t)(b * CC + c)) * HW + p0 + pp];
    }
    for (int i = t; i < 3 * HW; i += 256) imgs[i] = img[i];
    __syncthreads();

    if (t < PT) {
        float s = 0.f;
        #pragma unroll
        for (int c = 0; c < CC; ++c) { const float v = un[c * PT + t]; s += v * v; }
        z1sqs[t] = s;
    }

    // ---- phase A: GEMM, thread t owns q = 4t..4t+3 for all 8 p ----
    const float4* __restrict__ z2f4 =
        reinterpret_cast<const float4*>(z2 + (size_t)b * CC * HW);
    float4 acc[PT];
    #pragma unroll
    for (int pp = 0; pp < PT; ++pp) acc[pp] = make_float4(0.f, 0.f, 0.f, 0.f);
    float4 sq = make_float4(0.f, 0.f, 0.f, 0.f);

    #pragma unroll 8
    for (int k = 0; k < CC; ++k) {
        const float4 bv = z2f4[k * (HW / 4) + t];
        sq.x = fmaf(bv.x, bv.x, sq.x);
        sq.y = fmaf(bv.y, bv.y, sq.y);
        sq.z = fmaf(bv.z, bv.z, sq.z);
        sq.w = fmaf(bv.w, bv.w, sq.w);
        const float4 a03 = reinterpret_cast<const float4*>(un)[k * 2];
        const float4 a47 = reinterpret_cast<const float4*>(un)[k * 2 + 1];
        const float av[8] = {a03.x, a03.y, a03.z, a03.w, a47.x, a47.y, a47.z, a47.w};
        #pragma unroll
        for (int pp = 0; pp < PT; ++pp) {
            acc[pp].x = fmaf(av[pp], bv.x, acc[pp].x);
            acc[pp].y = fmaf(av[pp], bv.y, acc[pp].y);
            acc[pp].z = fmaf(av[pp], bv.z, acc[pp].z);
            acc[pp].w = fmaf(av[pp], bv.w, acc[pp].w);
        }
    }
    // fold 1/|z2_q| into D at write time (|z2_q| ~ 8, far from eps)
    const float4 rp = make_float4(
        1.0f / fmaxf(sqrtf(sq.x), 1e-20f), 1.0f / fmaxf(sqrtf(sq.y), 1e-20f),
        1.0f / fmaxf(sqrtf(sq.z), 1e-20f), 1.0f / fmaxf(sqrtf(sq.w), 1e-20f));
    float4* Dt4 = reinterpret_cast<float4*>(Dt_s);
    #pragma unroll
    for (int pp = 0; pp < PT; ++pp) {
        float4 v = acc[pp];
        v.x *= rp.x; v.y *= rp.y; v.z *= rp.z; v.w *= rp.w;
        Dt4[pp * (HW / 4) + t] = v;
    }
    __syncthreads();

    // ---- phase B: gather + weight + sim, all from LDS ----
    const float z1sq = z1sqs[pp_b];
    const float rz1  = 1.0f / fmaxf(sqrtf(z1sq), 1e-20f);
    const float cen0 = imgs[p_b], cen1 = imgs[HW + p_b], cen2 = imgs[2 * HW + p_b];
    const float hp = (float)(p_b >> 5), wp = (float)(p_b & 31);

    float se = 0.f, sr = 0.f;
    float cosv[8];
    #pragma unroll
    for (int j = 0; j < 8; ++j) {
        const int q = rr[j] * WW + cc_[j];
        const float dh = hp - (float)rr[j], dw = wp - (float)cc_[j];
        se += dh * dh + dw * dw;
        const float d0 = cen0 - imgs[q];
        const float d1 = cen1 - imgs[HW + q];
        const float d2 = cen2 - imgs[2 * HW + q];
        sr += d0 * d0 + d1 * d1 + d2 * d2;
        cosv[j] = Dt_s[pp_b * HW + q] * rz1;
    }
    // reduce over the 32 lanes sharing this p (xor<=16 stays in half-wave)
    #pragma unroll
    for (int off = 16; off; off >>= 1) {
        se += __shfl_xor(se, off);
        sr += __shfl_xor(sr, off);
    }
    const float euc_norm = sqrtf((float)((HH - 1) * (HH - 1) + (WW - 1) * (WW - 1)));
    const float weight = sqrtf(se) / euc_norm * FACTOR +
                         sqrtf(sr) / sqrtf(3.0f) * (1.0f - FACTOR);
    __syncthreads();   // As_s (union) dead; safe to write simpart
    #pragma unroll
    for (int j = 0; j < 8; ++j)
        un[pp_b * NEGN + lane32 + 32 * j] = fminf(fabsf(cosv[j] * weight), 1.0f);
    __syncthreads();

    // per-n sum over the 8 p's -> unique ws slot (no atomics, no memset)
    float s = 0.f;
    #pragma unroll
    for (int pp = 0; pp < PT; ++pp) s += un[pp * NEGN + t];
    ws[WS_PART + ((size_t)(b * NTILE + tile)) * NEGN + t] = s;

    if (t < PT) {
        const float c0 = z1sq / fmaxf(z1sq, EPSF);
        float s0 = fminf(fabsf(c0), 1.0f);
        #pragma unroll
        for (int off = 4; off; off >>= 1) s0 += __shfl_xor(s0, off);
        if (t == 0) ws[WS_S0PART + b * NTILE + tile] = s0;
    }
}

// ---------------------------------------------------------------------------
// Finalize: 8 blocks (one per b) reduce the 128 tile-partials; last block
// (device-scope counter) combines the 8 per-b results into out[0..2].
// ---------------------------------------------------------------------------
__global__ __launch_bounds__(256) void finalize(
    float* __restrict__ ws, float* __restrict__ out)
{
    const int t = threadIdx.x;
    const int b = blockIdx.x;
    const float* part = ws + WS_PART + (size_t)b * NTILE * NEGN;

    float s_bn = 0.f;
    #pragma unroll 8
    for (int tile = 0; tile < NTILE; ++tile)
        s_bn += part[(size_t)tile * NEGN + t];

    const float s = s_bn * (1.0f / HW) * (1.0f / TEMP);
    float ssum = s;
    float lsum = fmaxf(log1pf(-s), -100.0f);

    __shared__ float rs[4], rl[4], r0[2];
    #pragma unroll
    for (int off = 32; off; off >>= 1) {
        ssum += __shfl_down(ssum, off);
        lsum += __shfl_down(lsum, off);
    }
    if ((t & 63) == 0) { rs[t >> 6] = ssum; rl[t >> 6] = lsum; }

    if (t < 128) {
        float v = ws[WS_S0PART + b * NTILE + t];
        #pragma unroll
        for (int off = 32; off; off >>= 1) v += __shfl_down(v, off);
        if ((t & 63) == 0) r0[t >> 6] = v;
    }
    __syncthreads();

    if (t == 0) {
        ws[WS_BRES + b * 3 + 0] = rs[0] + rs[1] + rs[2] + rs[3];  // S_b
        ws[WS_BRES + b * 3 + 1] = rl[0] + rl[1] + rl[2] + rl[3];  // L_b
        ws[WS_BRES + b * 3 + 2] = r0[0] + r0[1];                  // sim0_b (sum over p)
        __threadfence();
        const int done = atomicAdd((int*)ws + WS_CNT, 1);
        if (done == BB - 1) {
            __threadfence();
            float S = 0.f, L = 0.f, logp = 0.f, s0m = 0.f;
            #pragma unroll
            for (int bb = 0; bb < BB; ++bb) {
                S += ws[WS_BRES + bb * 3 + 0];
                L += ws[WS_BRES + bb * 3 + 1];
                const float s0 = ws[WS_BRES + bb * 3 + 2] * (1.0f / HW);
                s0m  += s0;
                logp += fmaxf(logf(s0), -100.0f);
            }
            out[0] = -(logp + L) / ((float)(NEGN + 1) * (float)BB);
            out[1] = s0m / (float)BB;
            out[2] = S / (float)NEGN * TEMP / (float)BB;
        }
    }
}

extern "C" void kernel_launch(void* const* d_in, const int* in_sizes, int n_in,
                              void* d_out, int out_size, void* d_ws, size_t ws_size,
                              hipStream_t stream) {
    const float* v1   = (const float*)d_in[0];
    const float* v2   = (const float*)d_in[1];
    const float* img  = (const float*)d_in[2];
    const int*   nidx = (const int*)  d_in[3];
    float* ws = (float*)d_ws;

    contrastive_fused<<<BB * NTILE, 256, 0, stream>>>(v1, v2, img, nidx, ws);
    finalize<<<BB, 256, 0, stream>>>(ws, (float*)d_out);
}

// Round 4
// 114.822 us; speedup vs baseline: 1.0893x; 1.0893x over previous
//
#include <hip/hip_runtime.h>
#include <math.h>

#define BB 8
#define CC 64
#define HH 32
#define WW 32
#define HW 1024
#define NEGN 256
#define TEMP 2.0f
#define FACTOR 0.8f
#define EPSF 1e-8f
#define PT 8            // p-rows per block
#define NTILE 128       // blocks per sample = HW / PT

// ws layout (floats): accSim[BB*NEGN], accSim0[BB]
// (zeroed by init_acc each call; harness poisons ws with 0xAA before launch)

// ---------------------------------------------------------------------------
// init: zero the 8 KB accumulator region (9 blocks, launch-latency bound)
// ---------------------------------------------------------------------------
__global__ __launch_bounds__(256) void init_acc(float* __restrict__ acc) {
    const int i = blockIdx.x * 256 + threadIdx.x;
    if (i < BB * NEGN + BB) acc[i] = 0.f;
}

// ---------------------------------------------------------------------------
// Fused main kernel: one block per (b, 8-row p-tile).  LDS ~35 KB -> 4
// blocks/CU (16 waves/CU) so the L2-latency of the z2 stream is hidden.
// Phase A: D[pp][q] = sum_c z1[c,p]*z2[c,q] (coalesced float4 stream of
//          z2[b], L2-resident); 1/|z2_q| folded into D at LDS-write time.
// Phase B: per-(p,n) 4B LDS gather from Dt; img read via L1 (12 KB, hot);
//          weight via half-wave shuffle; sims accumulated with LDS atomics
//          into nacc[256] -> one global atomic per n per block.
// ---------------------------------------------------------------------------
__global__ __launch_bounds__(256) void contrastive_fused(
    const float* __restrict__ z1,    // (B, C, HW)
    const float* __restrict__ z2,    // (B, C, HW)
    const float* __restrict__ img,   // (3, HW)
    const int*   __restrict__ nidx,  // (B, 2, HW, NEG)
    float* __restrict__ accSim,      // (B, NEG)
    float* __restrict__ accSim0)     // (B)
{
    __shared__ float As_s[CC * PT];  // [k][pp]  2 KB
    __shared__ float Dt_s[PT * HW];  // [pp][q] 32 KB (cos numerator / |z2_q|)
    __shared__ float nacc[NEGN];     //          1 KB
    __shared__ float z1sqs[PT];

    const int t    = threadIdx.x;
    const int b    = blockIdx.x >> 7;
    const int tile = blockIdx.x & (NTILE - 1);
    const int p0   = tile * PT;

    const int lane32 = t & 31;   // n-group lane
    const int pp_b   = t >> 5;   // p handled by this thread in phase B
    const int p_b    = p0 + pp_b;

    // ---- prefetch nidx early (n = lane32 + 32*j; coalesced per half-wave) --
    int rr[8], cc_[8];
    const size_t nbase = ((size_t)(b * 2) * HW + p_b) * NEGN;
    #pragma unroll
    for (int j = 0; j < 8; ++j) {
        rr[j]  = nidx[nbase + lane32 + 32 * j];
        cc_[j] = nidx[nbase + (size_t)HW * NEGN + lane32 + 32 * j];
    }

    // ---- stage z1 panel; zero nacc ----
    #pragma unroll
    for (int i = t; i < CC * PT; i += 256) {
        const int c = i >> 3, pp = i & 7;
        As_s[i] = z1[((size_t)(b * CC + c)) * HW + p0 + pp];
    }
    nacc[t] = 0.f;
    __syncthreads();

    if (t < PT) {
        float s = 0.f;
        #pragma unroll
        for (int c = 0; c < CC; ++c) { const float v = As_s[c * PT + t]; s += v * v; }
        z1sqs[t] = s;
    }

    // ---- phase A: GEMM, thread t owns q = 4t..4t+3 for all 8 p ----
    const float4* __restrict__ z2f4 =
        reinterpret_cast<const float4*>(z2 + (size_t)b * CC * HW);
    float4 acc[PT];
    #pragma unroll
    for (int pp = 0; pp < PT; ++pp) acc[pp] = make_float4(0.f, 0.f, 0.f, 0.f);
    float4 sq = make_float4(0.f, 0.f, 0.f, 0.f);

    #pragma unroll 8
    for (int k = 0; k < CC; ++k) {
        const float4 bv = z2f4[k * (HW / 4) + t];
        sq.x = fmaf(bv.x, bv.x, sq.x);
        sq.y = fmaf(bv.y, bv.y, sq.y);
        sq.z = fmaf(bv.z, bv.z, sq.z);
        sq.w = fmaf(bv.w, bv.w, sq.w);
        const float4 a03 = reinterpret_cast<const float4*>(As_s)[k * 2];
        const float4 a47 = reinterpret_cast<const float4*>(As_s)[k * 2 + 1];
        const float av[8] = {a03.x, a03.y, a03.z, a03.w, a47.x, a47.y, a47.z, a47.w};
        #pragma unroll
        for (int pp = 0; pp < PT; ++pp) {
            acc[pp].x = fmaf(av[pp], bv.x, acc[pp].x);
            acc[pp].y = fmaf(av[pp], bv.y, acc[pp].y);
            acc[pp].z = fmaf(av[pp], bv.z, acc[pp].z);
            acc[pp].w = fmaf(av[pp], bv.w, acc[pp].w);
        }
    }
    // fold 1/|z2_q| into D at write time (|z2_q| ~ 8, far from eps)
    const float4 rp = make_float4(
        1.0f / fmaxf(sqrtf(sq.x), 1e-20f), 1.0f / fmaxf(sqrtf(sq.y), 1e-20f),
        1.0f / fmaxf(sqrtf(sq.z), 1e-20f), 1.0f / fmaxf(sqrtf(sq.w), 1e-20f));
    float4* Dt4 = reinterpret_cast<float4*>(Dt_s);
    #pragma unroll
    for (int pp = 0; pp < PT; ++pp) {
        float4 v = acc[pp];
        v.x *= rp.x; v.y *= rp.y; v.z *= rp.z; v.w *= rp.w;
        Dt4[pp * (HW / 4) + t] = v;
    }
    __syncthreads();

    // ---- phase B: gather + weight + sim; img via L1 (12 KB, resident) ----
    const float z1sq = z1sqs[pp_b];
    const float rz1  = 1.0f / fmaxf(sqrtf(z1sq), 1e-20f);
    const float cen0 = img[p_b], cen1 = img[HW + p_b], cen2 = img[2 * HW + p_b];
    const float hp = (float)(p_b >> 5), wp = (float)(p_b & 31);

    float se = 0.f, sr = 0.f;
    float cosv[8];
    #pragma unroll
    for (int j = 0; j < 8; ++j) {
        const int q = rr[j] * WW + cc_[j];
        const float dh = hp - (float)rr[j], dw = wp - (float)cc_[j];
        se += dh * dh + dw * dw;
        const float d0 = cen0 - img[q];
        const float d1 = cen1 - img[HW + q];
        const float d2 = cen2 - img[2 * HW + q];
        sr += d0 * d0 + d1 * d1 + d2 * d2;
        cosv[j] = Dt_s[pp_b * HW + q] * rz1;
    }
    // reduce over the 32 lanes sharing this p (xor<=16 stays in half-wave)
    #pragma unroll
    for (int off = 16; off; off >>= 1) {
        se += __shfl_xor(se, off);
        sr += __shfl_xor(sr, off);
    }
    const float euc_norm = sqrtf((float)((HH - 1) * (HH - 1) + (WW - 1) * (WW - 1)));
    const float weight = sqrtf(se) / euc_norm * FACTOR +
                         sqrtf(sr) / sqrtf(3.0f) * (1.0f - FACTOR);

    // accumulate over pp via LDS atomics (2-way same-address max -> cheap)
    #pragma unroll
    for (int j = 0; j < 8; ++j)
        atomicAdd(&nacc[lane32 + 32 * j], fminf(fabsf(cosv[j] * weight), 1.0f));
    __syncthreads();

    atomicAdd(accSim + b * NEGN + t, nacc[t]);

    if (t < PT) {
        const float c0 = z1sq / fmaxf(z1sq, EPSF);
        float s0 = fminf(fabsf(c0), 1.0f);
        #pragma unroll
        for (int off = 4; off; off >>= 1) s0 += __shfl_xor(s0, off);
        if (t == 0) atomicAdd(accSim0 + b, s0);
    }
}

// ---------------------------------------------------------------------------
// Finalize: 8 KB in, 3 floats out; one block.
// ---------------------------------------------------------------------------
__global__ __launch_bounds__(256) void finalize(
    const float* __restrict__ accSim,
    const float* __restrict__ accSim0,
    float* __restrict__ out)
{
    const int t = threadIdx.x;
    float ssum = 0.f, lsum = 0.f;
    #pragma unroll
    for (int b = 0; b < BB; ++b) {
        const float s = accSim[b * NEGN + t] * (1.0f / HW) * (1.0f / TEMP);
        ssum += s;
        lsum += fmaxf(log1pf(-s), -100.0f);
    }
    __shared__ float rs[4], rl[4];
    #pragma unroll
    for (int off = 32; off; off >>= 1) {
        ssum += __shfl_down(ssum, off);
        lsum += __shfl_down(lsum, off);
    }
    if ((t & 63) == 0) { rs[t >> 6] = ssum; rl[t >> 6] = lsum; }
    __syncthreads();

    if (t == 0) {
        const float S = rs[0] + rs[1] + rs[2] + rs[3];
        const float L = rl[0] + rl[1] + rl[2] + rl[3];
        float logpsum = 0.f, sim0sum = 0.f;
        #pragma unroll
        for (int b = 0; b < BB; ++b) {
            const float s0 = accSim0[b] * (1.0f / HW);
            sim0sum += s0;
            logpsum += fmaxf(logf(s0), -100.0f);
        }
        out[0] = -(logpsum + L) / ((float)(NEGN + 1) * (float)BB);
        out[1] = sim0sum / (float)BB;
        out[2] = S / (float)NEGN * TEMP / (float)BB;
    }
}

extern "C" void kernel_launch(void* const* d_in, const int* in_sizes, int n_in,
                              void* d_out, int out_size, void* d_ws, size_t ws_size,
                              hipStream_t stream) {
    const float* v1   = (const float*)d_in[0];
    const float* v2   = (const float*)d_in[1];
    const float* img  = (const float*)d_in[2];
    const int*   nidx = (const int*)  d_in[3];

    float* accSim  = (float*)d_ws;            // B*NEG
    float* accSim0 = accSim + BB * NEGN;      // B

    init_acc<<<(BB * NEGN + BB + 255) / 256, 256, 0, stream>>>(accSim);
    contrastive_fused<<<BB * NTILE, 256, 0, stream>>>(
        v1, v2, img, nidx, accSim, accSim0);
    finalize<<<1, 256, 0, stream>>>(accSim, accSim0, (float*)d_out);
}